// Round 1
// baseline (1334.699 us; speedup 1.0000x reference)
//
#include <hip/hip_runtime.h>
#include <cstddef>

#define BN_EPS 1e-5f

// ---------------------------------------------------------------------------
// Implicit-GEMM conv (VALID, stride 1) + eval-BN + ReLU.
//   in : [B, 256, H, W]  f32
//   wgt: [256, 256*KH*KW] f32 (row-major; matches [O,I,kh,kw] layout)
//   out: [B, 256, OH*OW] f32
// Tile: 64 oc x 64 p, K-tile 32, 256 threads, 4x4 register micro-tile.
// grid.x = B * 4 * NPT
// ---------------------------------------------------------------------------
template<int H, int W, int OH, int OW, int KH, int KW>
__global__ __launch_bounds__(256)
void conv_bn_relu_kernel(const float* __restrict__ in,
                         const float* __restrict__ wgt,
                         const float* __restrict__ bn_g,
                         const float* __restrict__ bn_b,
                         const float* __restrict__ bn_m,
                         const float* __restrict__ bn_v,
                         float* __restrict__ out)
{
    constexpr int CIN = 256;
    constexpr int KHW = KH * KW;
    constexpr int K   = CIN * KHW;
    constexpr int P   = OH * OW;
    constexpr int NPT = (P + 63) / 64;

    const int tid = threadIdx.x;
    int bid = blockIdx.x;
    const int pt  = bid % NPT; bid /= NPT;
    const int oct = bid & 3;
    const int b   = bid >> 2;
    const int oc0 = oct * 64;
    const int p0  = pt * 64;

    __shared__ float As[32][68];   // [k][oc]  (+4 pad keeps 16B alignment)
    __shared__ float Bs[32][68];   // [k][p]

    // B-tile (im2col) load mapping: fixed output position per thread
    const int pl  = tid & 63;
    const int kk0 = tid >> 6;               // 0..3
    const int p   = p0 + pl;
    const int pc  = (p < P) ? p : (P - 1);  // clamp; tail guarded at store
    const int oh  = pc / OW;
    const int ow  = pc - oh * OW;
    const float* inb = in + (size_t)b * CIN * H * W + (size_t)oh * W + ow;

    // A-tile (weights) load mapping: 4 threads per oc row, 8 k each
    const int aoc = tid >> 2;               // 0..63
    const int akb = (tid & 3) * 8;          // 0,8,16,24
    const float* wrow = wgt + (size_t)(oc0 + aoc) * K + akb;

    const int tx = tid & 15;                // p micro-tile
    const int ty = tid >> 4;                // oc micro-tile

    float acc[4][4] = {};

    for (int k0 = 0; k0 < K; k0 += 32) {
        float4 w0 = *(const float4*)(wrow + k0);
        float4 w1 = *(const float4*)(wrow + k0 + 4);
        float bv[8];
        #pragma unroll
        for (int i = 0; i < 8; ++i) {
            const int k  = k0 + kk0 + i * 4;
            const int ic = k / KHW;
            const int r  = k - ic * KHW;
            const int kh = r / KW;
            const int kw = r - kh * KW;
            bv[i] = inb[(size_t)ic * (H * W) + kh * W + kw];
        }
        __syncthreads();
        As[akb + 0][aoc] = w0.x; As[akb + 1][aoc] = w0.y;
        As[akb + 2][aoc] = w0.z; As[akb + 3][aoc] = w0.w;
        As[akb + 4][aoc] = w1.x; As[akb + 5][aoc] = w1.y;
        As[akb + 6][aoc] = w1.z; As[akb + 7][aoc] = w1.w;
        #pragma unroll
        for (int i = 0; i < 8; ++i) Bs[kk0 + i * 4][pl] = bv[i];
        __syncthreads();

        #pragma unroll
        for (int kk = 0; kk < 32; ++kk) {
            float4 av = *(const float4*)&As[kk][ty * 4];
            float4 bw = *(const float4*)&Bs[kk][tx * 4];
            const float aa[4] = {av.x, av.y, av.z, av.w};
            const float bb[4] = {bw.x, bw.y, bw.z, bw.w};
            #pragma unroll
            for (int i = 0; i < 4; ++i)
                #pragma unroll
                for (int j = 0; j < 4; ++j)
                    acc[i][j] += aa[i] * bb[j];
        }
    }

    #pragma unroll
    for (int i = 0; i < 4; ++i) {
        const int oc = oc0 + ty * 4 + i;
        const float sc = bn_g[oc] * rsqrtf(bn_v[oc] + BN_EPS);
        const float sh = bn_b[oc] - bn_m[oc] * sc;
        #pragma unroll
        for (int j = 0; j < 4; ++j) {
            const int pp = p0 + tx * 4 + j;
            if (pp < P)
                out[((size_t)b * 256 + oc) * P + pp] = fmaxf(acc[i][j] * sc + sh, 0.f);
        }
    }
}

// ---------------------------------------------------------------------------
// Depthwise cross-correlation: s [BC,29,29] (x) k [BC,5,5] -> [BC,25,25]
// One block per (b,c).
// ---------------------------------------------------------------------------
__global__ __launch_bounds__(256)
void xcorr_kernel(const float* __restrict__ s, const float* __restrict__ k,
                  float* __restrict__ out)
{
    const int bc = blockIdx.x;
    const float* sp = s + (size_t)bc * 841;
    const float* kp = k + (size_t)bc * 25;
    __shared__ float ss[841];
    __shared__ float kk[25];
    const int tid = threadIdx.x;
    for (int i = tid; i < 841; i += 256) ss[i] = sp[i];
    if (tid < 25) kk[tid] = kp[tid];
    __syncthreads();
    for (int p = tid; p < 625; p += 256) {
        const int oh = p / 25;
        const int ow = p - oh * 25;
        float acc = 0.f;
        #pragma unroll
        for (int i = 0; i < 5; ++i)
            #pragma unroll
            for (int j = 0; j < 5; ++j)
                acc += ss[(oh + i) * 29 + ow + j] * kk[i * 5 + j];
        out[(size_t)bc * 625 + p] = acc;
    }
}

// ---------------------------------------------------------------------------
// Final 10-channel 1x1 conv + bias: out[b,o,p] = h2[o,:] . y[b,:,p] + h2b[o]
// grid = B * 3 tiles of 256 positions.
// ---------------------------------------------------------------------------
__global__ __launch_bounds__(256)
void head2_kernel(const float* __restrict__ y, const float* __restrict__ h2,
                  const float* __restrict__ h2b, float* __restrict__ out)
{
    __shared__ float h2s[2560];
    const int tid = threadIdx.x;
    for (int i = tid; i < 2560; i += 256) h2s[i] = h2[i];
    const int bid = blockIdx.x;
    const int pt = bid % 3;
    const int b  = bid / 3;
    const int p  = pt * 256 + tid;
    __syncthreads();
    float acc[10];
    #pragma unroll
    for (int q = 0; q < 10; ++q) acc[q] = h2b[q];
    const bool valid = (p < 625);
    const int pc = valid ? p : 624;
    const float* yb = y + (size_t)b * 256 * 625;
    for (int oc = 0; oc < 256; ++oc) {
        const float v = yb[(size_t)oc * 625 + pc];
        #pragma unroll
        for (int q = 0; q < 10; ++q) acc[q] += h2s[q * 256 + oc] * v;
    }
    if (valid) {
        #pragma unroll
        for (int q = 0; q < 10; ++q)
            out[((size_t)b * 10 + q) * 625 + p] = acc[q];
    }
}

// ---------------------------------------------------------------------------
extern "C" void kernel_launch(void* const* d_in, const int* in_sizes, int n_in,
                              void* d_out, int out_size, void* d_ws, size_t ws_size,
                              hipStream_t stream)
{
    const float* kin  = (const float*)d_in[0];   // [B,256,7,7]
    const float* srch = (const float*)d_in[1];   // [B,256,31,31]
    const float* ck_w = (const float*)d_in[2];
    const float* ck_g = (const float*)d_in[3];
    const float* ck_b = (const float*)d_in[4];
    const float* ck_m = (const float*)d_in[5];
    const float* ck_v = (const float*)d_in[6];
    const float* cs_w = (const float*)d_in[7];
    const float* cs_g = (const float*)d_in[8];
    const float* cs_b = (const float*)d_in[9];
    const float* cs_m = (const float*)d_in[10];
    const float* cs_v = (const float*)d_in[11];
    const float* h1_w = (const float*)d_in[12];  // [256,256]
    const float* h_g  = (const float*)d_in[13];
    const float* h_b  = (const float*)d_in[14];
    const float* h_m  = (const float*)d_in[15];
    const float* h_v  = (const float*)d_in[16];
    const float* h2_w = (const float*)d_in[17];  // [10,256]
    const float* h2_b = (const float*)d_in[18];  // [10]

    const int B = in_sizes[0] / (256 * 7 * 7);   // 64

    // Workspace layout (floats):
    //   kf [B*256*25] | sf [B*256*841] | xc [B*256*625]
    //   y  [B*256*625] aliases kf+sf region (dead after xcorr)
    float* ws = (float*)d_ws;
    float* kf = ws;
    float* sf = kf + (size_t)B * 256 * 25;
    float* xc = sf + (size_t)B * 256 * 841;
    float* y  = ws;

    dim3 blk(256, 1, 1);

    // kernel branch: 7x7 -> 5x5    (P=25, NPT=1)
    hipLaunchKernelGGL((conv_bn_relu_kernel<7, 7, 5, 5, 3, 3>),
                       dim3(B * 4 * 1), blk, 0, stream,
                       kin, ck_w, ck_g, ck_b, ck_m, ck_v, kf);
    // search branch: 31x31 -> 29x29 (P=841, NPT=14)
    hipLaunchKernelGGL((conv_bn_relu_kernel<31, 31, 29, 29, 3, 3>),
                       dim3(B * 4 * 14), blk, 0, stream,
                       srch, cs_w, cs_g, cs_b, cs_m, cs_v, sf);
    // depthwise xcorr: 29x29 (x) 5x5 -> 25x25
    hipLaunchKernelGGL(xcorr_kernel, dim3(B * 256), blk, 0, stream, sf, kf, xc);
    // head 1x1 conv + BN + ReLU as GEMM (P=625, NPT=10)
    hipLaunchKernelGGL((conv_bn_relu_kernel<25, 25, 25, 25, 1, 1>),
                       dim3(B * 4 * 10), blk, 0, stream,
                       xc, h1_w, h_g, h_b, h_m, h_v, y);
    // final 10-channel projection + bias
    hipLaunchKernelGGL(head2_kernel, dim3(B * 3), blk, 0, stream,
                       y, h2_w, h2_b, (float*)d_out);
}

// Round 2
// 380.127 us; speedup vs baseline: 3.5112x; 3.5112x over previous
//
#include <hip/hip_runtime.h>
#include <cstddef>
#include <cstdint>

#define BN_EPS 1e-5f

typedef __attribute__((ext_vector_type(8))) __bf16 bf16x8;
typedef __attribute__((ext_vector_type(4))) float f32x4;

__device__ inline unsigned short f2bf(float f) {
    unsigned u = __builtin_bit_cast(unsigned, f);
    unsigned r = (u + 0x7fff + ((u >> 16) & 1)) >> 16;
    return (unsigned short)r;
}

#define GLDS16(g, l)                                                        \
    __builtin_amdgcn_global_load_lds(                                       \
        (const __attribute__((address_space(1))) void*)(g),                 \
        (__attribute__((address_space(3))) void*)(l), 16, 0, 0)

// ---------------------------------------------------------------------------
// search [B,256,31,31] f32  ->  NHWC bf16 [B,31,31,256]
// block = (b,h); 256 threads = channel
// ---------------------------------------------------------------------------
__global__ __launch_bounds__(256)
void nhwc_bf16_kernel(const float* __restrict__ in, unsigned short* __restrict__ out)
{
    const int bh = blockIdx.x;            // b*31 + h
    const int b  = bh / 31, h = bh % 31;
    const int c  = threadIdx.x;
    __shared__ unsigned short lds[31][256];
    const float* src = in + ((size_t)(b * 256 + c) * 31 + h) * 31;
    #pragma unroll
    for (int w = 0; w < 31; ++w) lds[w][c] = f2bf(src[w]);
    __syncthreads();
    unsigned short* dst = out + (size_t)bh * 31 * 256 + c;
    #pragma unroll
    for (int w = 0; w < 31; ++w) dst[w * 256] = lds[w][c];
}

// ---------------------------------------------------------------------------
// cs_w [oc=256][ic=256][3][3] f32 -> wT [9][oc=256][ic=256] bf16
// ---------------------------------------------------------------------------
__global__ __launch_bounds__(256)
void wreorder_kernel(const float* __restrict__ w, unsigned short* __restrict__ o)
{
    const int i = blockIdx.x * 256 + threadIdx.x;   // ((khkw*256)+oc)*256+ic
    if (i >= 9 * 256 * 256) return;
    const int ic = i & 255;
    const int t  = i >> 8;
    const int oc = t & 255;
    const int khkw = t >> 8;
    o[i] = f2bf(w[(size_t)(oc * 256 + ic) * 9 + khkw]);
}

// ---------------------------------------------------------------------------
// MFMA implicit-GEMM conv 3x3 VALID + BN + ReLU (search branch)
//   s16: NHWC bf16 [B,31,31,256]
//   wT : bf16 [9][256 oc][256 ic]
//   out: f32 [B,256,841]
// Tile: 128 oc x 128 pos, BK=64 ic, 9 taps outer. 256 thr = 4 waves (2x2).
// LDS tiles [row][64] bf16 with granule XOR-swizzle (g ^= row&7), staged via
// global_load_lds (linear dest, inverse-swizzled per-lane global source).
// grid = B * 2 * 7
// ---------------------------------------------------------------------------
__global__ __launch_bounds__(256)
void conv_s_mfma_kernel(const unsigned short* __restrict__ s16,
                        const unsigned short* __restrict__ wT,
                        const float* __restrict__ bn_g,
                        const float* __restrict__ bn_b,
                        const float* __restrict__ bn_m,
                        const float* __restrict__ bn_v,
                        float* __restrict__ out)
{
    __shared__ __align__(16) unsigned short Alds[128 * 64];
    __shared__ __align__(16) unsigned short Blds[128 * 64];

    const int tid  = threadIdx.x;
    const int lane = tid & 63;
    const int wid  = tid >> 6;

    int bid = blockIdx.x;
    const int pt  = bid % 7;  bid /= 7;
    const int oct = bid & 1;
    const int b   = bid >> 1;
    const int oc0 = oct * 128;
    const int p0  = pt * 128;

    // ---- staging maps (4 wave-issues each for A and B; 8 rows per issue) ----
    int aoff[4];        // elem offset into wT slice (add khkw*65536 + ic0)
    int bohw[4];        // (b*31+oh)*31+ow  (add kh*31+kw, then *256)
    int bgs8[4];        // swizzled granule *8 for B
    int ldsrow[4];      // elem offset of wave-issue LDS base
    #pragma unroll
    for (int i = 0; i < 4; ++i) {
        const int r  = i * 32 + wid * 8 + (lane >> 3);
        const int gs = (lane & 7) ^ (r & 7);
        aoff[i] = (oc0 + r) * 256 + gs * 8;
        int p = p0 + r; if (p > 840) p = 840;
        const int oh = p / 29, ow = p - oh * 29;
        bohw[i] = (b * 31 + oh) * 31 + ow;
        bgs8[i] = gs * 8;
        ldsrow[i] = (i * 32 + wid * 8) * 64;
    }

    // ---- compute-phase maps ----
    const int q   = lane >> 4;          // 0..3
    const int lr  = lane & 15;
    const int wm0 = (wid >> 1) * 64;    // oc sub-tile
    const int wn0 = (wid & 1) * 64;     // pos sub-tile
    const int g0  = q ^ (lane & 7);         // granule for ks=0
    const int g1  = (4 + q) ^ (lane & 7);   // granule for ks=1
    const unsigned short* Abase = &Alds[(wm0 + lr) * 64];
    const unsigned short* Bbase = &Blds[(wn0 + lr) * 64];

    f32x4 acc[4][4] = {};

    for (int khkw = 0; khkw < 9; ++khkw) {
        const int kh = khkw / 3;
        const int kw = khkw - kh * 3;
        const size_t wslice = (size_t)khkw * 65536;
        const int tapadd = kh * 31 + kw;
        for (int ics = 0; ics < 4; ++ics) {
            const int ic0 = ics * 64;
            __syncthreads();
            #pragma unroll
            for (int i = 0; i < 4; ++i) {
                GLDS16(wT + wslice + aoff[i] + ic0, &Alds[ldsrow[i]]);
                GLDS16(s16 + (size_t)(bohw[i] + tapadd) * 256 + ic0 + bgs8[i],
                       &Blds[ldsrow[i]]);
            }
            __syncthreads();

            bf16x8 bfr[4][2];
            #pragma unroll
            for (int n = 0; n < 4; ++n) {
                bfr[n][0] = *(const bf16x8*)(Bbase + n * 1024 + g0 * 8);
                bfr[n][1] = *(const bf16x8*)(Bbase + n * 1024 + g1 * 8);
            }
            #pragma unroll
            for (int m = 0; m < 4; ++m) {
                bf16x8 a0 = *(const bf16x8*)(Abase + m * 1024 + g0 * 8);
                bf16x8 a1 = *(const bf16x8*)(Abase + m * 1024 + g1 * 8);
                #pragma unroll
                for (int n = 0; n < 4; ++n) {
                    acc[m][n] = __builtin_amdgcn_mfma_f32_16x16x32_bf16(
                                    a0, bfr[n][0], acc[m][n], 0, 0, 0);
                    acc[m][n] = __builtin_amdgcn_mfma_f32_16x16x32_bf16(
                                    a1, bfr[n][1], acc[m][n], 0, 0, 0);
                }
            }
        }
    }

    // ---- epilogue: BN + ReLU, C layout col=lane&15 (pos), row=q*4+reg (oc) --
    #pragma unroll
    for (int m = 0; m < 4; ++m) {
        const int ocm = oc0 + wm0 + m * 16 + q * 4;
        float sc[4], sh[4];
        #pragma unroll
        for (int r = 0; r < 4; ++r) {
            sc[r] = bn_g[ocm + r] * rsqrtf(bn_v[ocm + r] + BN_EPS);
            sh[r] = bn_b[ocm + r] - bn_m[ocm + r] * sc[r];
        }
        #pragma unroll
        for (int n = 0; n < 4; ++n) {
            const int p = p0 + wn0 + n * 16 + lr;
            if (p < 841) {
                #pragma unroll
                for (int r = 0; r < 4; ++r)
                    out[((size_t)(b * 256 + ocm + r)) * 841 + p] =
                        fmaxf(acc[m][n][r] * sc[r] + sh[r], 0.f);
            }
        }
    }
}

// ---------------------------------------------------------------------------
// fp32 implicit-GEMM conv + BN + ReLU (kernel branch + head1) — round-1 kernel
// ---------------------------------------------------------------------------
template<int H, int W, int OH, int OW, int KH, int KW>
__global__ __launch_bounds__(256)
void conv_bn_relu_kernel(const float* __restrict__ in,
                         const float* __restrict__ wgt,
                         const float* __restrict__ bn_g,
                         const float* __restrict__ bn_b,
                         const float* __restrict__ bn_m,
                         const float* __restrict__ bn_v,
                         float* __restrict__ out)
{
    constexpr int CIN = 256;
    constexpr int KHW = KH * KW;
    constexpr int K   = CIN * KHW;
    constexpr int P   = OH * OW;
    constexpr int NPT = (P + 63) / 64;

    const int tid = threadIdx.x;
    int bid = blockIdx.x;
    const int pt  = bid % NPT; bid /= NPT;
    const int oct = bid & 3;
    const int b   = bid >> 2;
    const int oc0 = oct * 64;
    const int p0  = pt * 64;

    __shared__ float As[32][68];
    __shared__ float Bs[32][68];

    const int pl  = tid & 63;
    const int kk0 = tid >> 6;
    const int p   = p0 + pl;
    const int pc  = (p < P) ? p : (P - 1);
    const int oh  = pc / OW;
    const int ow  = pc - oh * OW;
    const float* inb = in + (size_t)b * CIN * H * W + (size_t)oh * W + ow;

    const int aoc = tid >> 2;
    const int akb = (tid & 3) * 8;
    const float* wrow = wgt + (size_t)(oc0 + aoc) * K + akb;

    const int tx = tid & 15;
    const int ty = tid >> 4;

    float acc[4][4] = {};

    for (int k0 = 0; k0 < K; k0 += 32) {
        float4 w0 = *(const float4*)(wrow + k0);
        float4 w1 = *(const float4*)(wrow + k0 + 4);
        float bv[8];
        #pragma unroll
        for (int i = 0; i < 8; ++i) {
            const int k  = k0 + kk0 + i * 4;
            const int ic = k / KHW;
            const int r  = k - ic * KHW;
            const int kh = r / KW;
            const int kw = r - kh * KW;
            bv[i] = inb[(size_t)ic * (H * W) + kh * W + kw];
        }
        __syncthreads();
        As[akb + 0][aoc] = w0.x; As[akb + 1][aoc] = w0.y;
        As[akb + 2][aoc] = w0.z; As[akb + 3][aoc] = w0.w;
        As[akb + 4][aoc] = w1.x; As[akb + 5][aoc] = w1.y;
        As[akb + 6][aoc] = w1.z; As[akb + 7][aoc] = w1.w;
        #pragma unroll
        for (int i = 0; i < 8; ++i) Bs[kk0 + i * 4][pl] = bv[i];
        __syncthreads();

        #pragma unroll
        for (int kk = 0; kk < 32; ++kk) {
            float4 av = *(const float4*)&As[kk][ty * 4];
            float4 bw = *(const float4*)&Bs[kk][tx * 4];
            const float aa[4] = {av.x, av.y, av.z, av.w};
            const float bb[4] = {bw.x, bw.y, bw.z, bw.w};
            #pragma unroll
            for (int i = 0; i < 4; ++i)
                #pragma unroll
                for (int j = 0; j < 4; ++j)
                    acc[i][j] += aa[i] * bb[j];
        }
    }

    #pragma unroll
    for (int i = 0; i < 4; ++i) {
        const int oc = oc0 + ty * 4 + i;
        const float sc = bn_g[oc] * rsqrtf(bn_v[oc] + BN_EPS);
        const float sh = bn_b[oc] - bn_m[oc] * sc;
        #pragma unroll
        for (int j = 0; j < 4; ++j) {
            const int pp = p0 + tx * 4 + j;
            if (pp < P)
                out[((size_t)b * 256 + oc) * P + pp] = fmaxf(acc[i][j] * sc + sh, 0.f);
        }
    }
}

// ---------------------------------------------------------------------------
__global__ __launch_bounds__(256)
void xcorr_kernel(const float* __restrict__ s, const float* __restrict__ k,
                  float* __restrict__ out)
{
    const int bc = blockIdx.x;
    const float* sp = s + (size_t)bc * 841;
    const float* kp = k + (size_t)bc * 25;
    __shared__ float ss[841];
    __shared__ float kk[25];
    const int tid = threadIdx.x;
    for (int i = tid; i < 841; i += 256) ss[i] = sp[i];
    if (tid < 25) kk[tid] = kp[tid];
    __syncthreads();
    for (int p = tid; p < 625; p += 256) {
        const int oh = p / 25;
        const int ow = p - oh * 25;
        float acc = 0.f;
        #pragma unroll
        for (int i = 0; i < 5; ++i)
            #pragma unroll
            for (int j = 0; j < 5; ++j)
                acc += ss[(oh + i) * 29 + ow + j] * kk[i * 5 + j];
        out[(size_t)bc * 625 + p] = acc;
    }
}

// ---------------------------------------------------------------------------
__global__ __launch_bounds__(256)
void head2_kernel(const float* __restrict__ y, const float* __restrict__ h2,
                  const float* __restrict__ h2b, float* __restrict__ out)
{
    __shared__ float h2s[2560];
    const int tid = threadIdx.x;
    for (int i = tid; i < 2560; i += 256) h2s[i] = h2[i];
    const int bid = blockIdx.x;
    const int pt = bid % 3;
    const int b  = bid / 3;
    const int p  = pt * 256 + tid;
    __syncthreads();
    float acc[10];
    #pragma unroll
    for (int q = 0; q < 10; ++q) acc[q] = h2b[q];
    const bool valid = (p < 625);
    const int pc = valid ? p : 624;
    const float* yb = y + (size_t)b * 256 * 625;
    for (int oc = 0; oc < 256; ++oc) {
        const float v = yb[(size_t)oc * 625 + pc];
        #pragma unroll
        for (int q = 0; q < 10; ++q) acc[q] += h2s[q * 256 + oc] * v;
    }
    if (valid) {
        #pragma unroll
        for (int q = 0; q < 10; ++q)
            out[((size_t)b * 10 + q) * 625 + p] = acc[q];
    }
}

// ---------------------------------------------------------------------------
extern "C" void kernel_launch(void* const* d_in, const int* in_sizes, int n_in,
                              void* d_out, int out_size, void* d_ws, size_t ws_size,
                              hipStream_t stream)
{
    const float* kin  = (const float*)d_in[0];
    const float* srch = (const float*)d_in[1];
    const float* ck_w = (const float*)d_in[2];
    const float* ck_g = (const float*)d_in[3];
    const float* ck_b = (const float*)d_in[4];
    const float* ck_m = (const float*)d_in[5];
    const float* ck_v = (const float*)d_in[6];
    const float* cs_w = (const float*)d_in[7];
    const float* cs_g = (const float*)d_in[8];
    const float* cs_b = (const float*)d_in[9];
    const float* cs_m = (const float*)d_in[10];
    const float* cs_v = (const float*)d_in[11];
    const float* h1_w = (const float*)d_in[12];
    const float* h_g  = (const float*)d_in[13];
    const float* h_b  = (const float*)d_in[14];
    const float* h_m  = (const float*)d_in[15];
    const float* h_v  = (const float*)d_in[16];
    const float* h2_w = (const float*)d_in[17];
    const float* h2_b = (const float*)d_in[18];

    const int B = in_sizes[0] / (256 * 7 * 7);   // 64

    // Workspace (floats):
    //   kf [B*256*25] | sf [B*256*841] | xc [B*256*625]
    //   s16 (bf16 NHWC search) + wT (bf16 weights) alias the xc region
    //   y aliases kf+sf region (dead after xcorr)
    float* ws = (float*)d_ws;
    float* kf = ws;
    float* sf = kf + (size_t)B * 256 * 25;
    float* xc = sf + (size_t)B * 256 * 841;
    float* y  = ws;
    unsigned short* s16 = (unsigned short*)xc;                   // B*31*31*256 bf16
    unsigned short* wT  = (unsigned short*)(xc + (size_t)B * 31 * 31 * 128);

    dim3 blk(256, 1, 1);

    // prep: NHWC bf16 search + reordered bf16 weights
    hipLaunchKernelGGL(nhwc_bf16_kernel, dim3(B * 31), blk, 0, stream, srch, s16);
    hipLaunchKernelGGL(wreorder_kernel, dim3(9 * 256), blk, 0, stream, cs_w, wT);
    // kernel branch (fp32): 7x7 -> 5x5
    hipLaunchKernelGGL((conv_bn_relu_kernel<7, 7, 5, 5, 3, 3>),
                       dim3(B * 4 * 1), blk, 0, stream,
                       kin, ck_w, ck_g, ck_b, ck_m, ck_v, kf);
    // search branch (bf16 MFMA): 31x31 -> 29x29
    hipLaunchKernelGGL(conv_s_mfma_kernel, dim3(B * 2 * 7), blk, 0, stream,
                       s16, wT, cs_g, cs_b, cs_m, cs_v, sf);
    // depthwise xcorr
    hipLaunchKernelGGL(xcorr_kernel, dim3(B * 256), blk, 0, stream, sf, kf, xc);
    // head 1x1 conv + BN + ReLU (fp32 GEMM)
    hipLaunchKernelGGL((conv_bn_relu_kernel<25, 25, 25, 25, 1, 1>),
                       dim3(B * 4 * 10), blk, 0, stream,
                       xc, h1_w, h_g, h_b, h_m, h_v, y);
    // final projection
    hipLaunchKernelGGL(head2_kernel, dim3(B * 3), blk, 0, stream,
                       y, h2_w, h2_b, (float*)d_out);
}

// Round 3
// 218.191 us; speedup vs baseline: 6.1171x; 1.7422x over previous
//
#include <hip/hip_runtime.h>
#include <cstddef>
#include <cstdint>

#define BN_EPS 1e-5f

typedef __attribute__((ext_vector_type(8))) __bf16 bf16x8;
typedef __attribute__((ext_vector_type(4))) float f32x4;

__device__ inline unsigned short f2bf(float f) {
    unsigned u = __builtin_bit_cast(unsigned, f);
    unsigned r = (u + 0x7fff + ((u >> 16) & 1)) >> 16;
    return (unsigned short)r;
}

#define GLDS16(g, l)                                                        \
    __builtin_amdgcn_global_load_lds(                                       \
        (const __attribute__((address_space(1))) void*)(g),                 \
        (__attribute__((address_space(3))) void*)(l), 16, 0, 0)

// ---------------------------------------------------------------------------
// NCHW f32 -> NHWC bf16.  grid = B*H, threads = 256 channels.
// ---------------------------------------------------------------------------
template<int H, int W>
__global__ __launch_bounds__(256)
void nhwc_kernel(const float* __restrict__ in, unsigned short* __restrict__ out)
{
    const int bh = blockIdx.x;
    const int b  = bh / H, h = bh % H;
    const int c  = threadIdx.x;
    __shared__ unsigned short lds[W][256];
    const float* src = in + ((size_t)(b * 256 + c) * H + h) * W;
    #pragma unroll
    for (int w = 0; w < W; ++w) lds[w][c] = f2bf(src[w]);
    __syncthreads();
    unsigned short* dst = out + ((size_t)(b * H + h)) * W * 256 + c;
    #pragma unroll
    for (int w = 0; w < W; ++w) dst[w * 256] = lds[w][c];
}

// ---------------------------------------------------------------------------
// All weight conversions in one kernel.
//   wTs/wTk: [O,I,3,3] f32 -> [9][oc][ic] bf16
//   h1w16  : [256,256] f32 -> bf16 (same layout)
//   h2w16  : [10,256]  f32 -> [16][256] bf16, rows 10..15 zero
// ---------------------------------------------------------------------------
__global__ __launch_bounds__(256)
void weights_prep_kernel(const float* __restrict__ cs_w, const float* __restrict__ ck_w,
                         const float* __restrict__ h1_w, const float* __restrict__ h2_w,
                         unsigned short* __restrict__ wTs, unsigned short* __restrict__ wTk,
                         unsigned short* __restrict__ h1w16, unsigned short* __restrict__ h2w16)
{
    const int i = blockIdx.x * 256 + threadIdx.x;
    if (i < 589824) {
        const int ic = i & 255, t = i >> 8, oc = t & 255, khkw = t >> 8;
        wTs[i] = f2bf(cs_w[(size_t)((oc << 8) + ic) * 9 + khkw]);
    } else if (i < 1179648) {
        const int j = i - 589824;
        const int ic = j & 255, t = j >> 8, oc = t & 255, khkw = t >> 8;
        wTk[j] = f2bf(ck_w[(size_t)((oc << 8) + ic) * 9 + khkw]);
    } else if (i < 1245184) {
        const int j = i - 1179648;
        h1w16[j] = f2bf(h1_w[j]);
    } else if (i < 1249280) {
        const int j = i - 1245184;
        const int oc = j >> 8, ic = j & 255;
        h2w16[j] = (oc < 10) ? f2bf(h2_w[oc * 256 + ic]) : (unsigned short)0;
    }
}

// ---------------------------------------------------------------------------
// Unified MFMA implicit-GEMM conv + BN (+ReLU).
//   bsrc: NHWC bf16 [B*IH*IW][256]   (for 1x1: [N][256])
//   wT  : bf16 [KH*KW][256 oc][256 ic]
//   out : OUT_NT ? bf16 [pos][256 oc] : f32 [b][256 oc][PPB]
// Global position space N = B*PPB; tile 128 oc x 128 pos, BK=64, taps outer.
// 4 waves (2x2), LDS granule XOR-swizzle staged via global_load_lds.
// grid = 2 * ceil(N/128)
// ---------------------------------------------------------------------------
template<int KH, int KW, int IH, int IW, int OW, int PPB, bool OUT_NT>
__global__ __launch_bounds__(256)
void conv_mfma_kernel(const unsigned short* __restrict__ bsrc,
                      const unsigned short* __restrict__ wT,
                      const float* __restrict__ bn_g,
                      const float* __restrict__ bn_b,
                      const float* __restrict__ bn_m,
                      const float* __restrict__ bn_v,
                      float* __restrict__ out_f32,
                      unsigned short* __restrict__ out_nt,
                      int N)
{
    constexpr int KHW = KH * KW;
    __shared__ __align__(16) unsigned short Alds[128 * 64];
    __shared__ __align__(16) unsigned short Blds[128 * 64];

    const int tid  = threadIdx.x;
    const int lane = tid & 63;
    const int wid  = tid >> 6;

    const int NPT = (N + 127) >> 7;
    const int bid = blockIdx.x;
    const int pt  = bid % NPT;
    const int oct = bid / NPT;
    const int oc0 = oct * 128;
    const int p0  = pt * 128;

    // ---- staging maps (4 wave-issues each; 8 rows per issue) ----
    int aoff[4], brow[4], bgs8[4], ldsrow[4];
    #pragma unroll
    for (int i = 0; i < 4; ++i) {
        const int r  = i * 32 + wid * 8 + (lane >> 3);
        const int gs = (lane & 7) ^ (r & 7);
        aoff[i] = (oc0 + r) * 256 + gs * 8;
        int pg = p0 + r; if (pg > N - 1) pg = N - 1;
        const int bb = pg / PPB;
        const int p  = pg - bb * PPB;
        const int oh = p / OW, ow = p - oh * OW;
        brow[i] = (bb * IH + oh) * IW + ow;
        bgs8[i] = gs * 8;
        ldsrow[i] = (i * 32 + wid * 8) * 64;
    }

    // ---- compute-phase maps ----
    const int q   = lane >> 4;
    const int lr  = lane & 15;
    const int wm0 = (wid >> 1) * 64;
    const int wn0 = (wid & 1) * 64;
    const int g0  = q ^ (lane & 7);
    const int g1  = (4 + q) ^ (lane & 7);
    const unsigned short* Abase = &Alds[(wm0 + lr) * 64];
    const unsigned short* Bbase = &Blds[(wn0 + lr) * 64];

    f32x4 acc[4][4] = {};

    for (int khkw = 0; khkw < KHW; ++khkw) {
        const int kh = khkw / KW;
        const int kw = khkw - kh * KW;
        const size_t wslice = (size_t)khkw * 65536;
        const int tapadd = kh * IW + kw;
        for (int ics = 0; ics < 4; ++ics) {
            const int ic0 = ics * 64;
            __syncthreads();
            #pragma unroll
            for (int i = 0; i < 4; ++i) {
                GLDS16(wT + wslice + aoff[i] + ic0, &Alds[ldsrow[i]]);
                GLDS16(bsrc + (size_t)(brow[i] + tapadd) * 256 + ic0 + bgs8[i],
                       &Blds[ldsrow[i]]);
            }
            __syncthreads();

            bf16x8 bfr[4][2];
            #pragma unroll
            for (int n = 0; n < 4; ++n) {
                bfr[n][0] = *(const bf16x8*)(Bbase + n * 1024 + g0 * 8);
                bfr[n][1] = *(const bf16x8*)(Bbase + n * 1024 + g1 * 8);
            }
            #pragma unroll
            for (int m = 0; m < 4; ++m) {
                bf16x8 a0 = *(const bf16x8*)(Abase + m * 1024 + g0 * 8);
                bf16x8 a1 = *(const bf16x8*)(Abase + m * 1024 + g1 * 8);
                #pragma unroll
                for (int n = 0; n < 4; ++n) {
                    acc[m][n] = __builtin_amdgcn_mfma_f32_16x16x32_bf16(
                                    a0, bfr[n][0], acc[m][n], 0, 0, 0);
                    acc[m][n] = __builtin_amdgcn_mfma_f32_16x16x32_bf16(
                                    a1, bfr[n][1], acc[m][n], 0, 0, 0);
                }
            }
        }
    }

    // ---- epilogue: BN + ReLU.  C: col=lane&15 (pos), row=q*4+reg (oc) ----
    #pragma unroll
    for (int m = 0; m < 4; ++m) {
        const int ocm = oc0 + wm0 + m * 16 + q * 4;
        float sc[4], sh[4];
        #pragma unroll
        for (int r = 0; r < 4; ++r) {
            sc[r] = bn_g[ocm + r] * rsqrtf(bn_v[ocm + r] + BN_EPS);
            sh[r] = bn_b[ocm + r] - bn_m[ocm + r] * sc[r];
        }
        #pragma unroll
        for (int n = 0; n < 4; ++n) {
            const int pg = p0 + wn0 + n * 16 + lr;
            if (pg < N) {
                if (OUT_NT) {
                    unsigned e0 = f2bf(fmaxf(acc[m][n][0] * sc[0] + sh[0], 0.f));
                    unsigned e1 = f2bf(fmaxf(acc[m][n][1] * sc[1] + sh[1], 0.f));
                    unsigned e2 = f2bf(fmaxf(acc[m][n][2] * sc[2] + sh[2], 0.f));
                    unsigned e3 = f2bf(fmaxf(acc[m][n][3] * sc[3] + sh[3], 0.f));
                    uint2 v; v.x = e0 | (e1 << 16); v.y = e2 | (e3 << 16);
                    *(uint2*)(out_nt + (size_t)pg * 256 + ocm) = v;
                } else {
                    const int bb = pg / PPB;
                    const int p  = pg - bb * PPB;
                    #pragma unroll
                    for (int r = 0; r < 4; ++r)
                        out_f32[((size_t)(bb * 256 + ocm + r)) * PPB + p] =
                            fmaxf(acc[m][n][r] * sc[r] + sh[r], 0.f);
                }
            }
        }
    }
}

// ---------------------------------------------------------------------------
// Depthwise xcorr: sf f32 [b][c][841] (x) kf f32 [b][c][25] -> xc2 bf16 [b*625+p][256]
// 8 channels per block; grid = B*32.
// ---------------------------------------------------------------------------
__global__ __launch_bounds__(256)
void xcorr_kernel(const float* __restrict__ sf, const float* __restrict__ kf,
                  unsigned short* __restrict__ xc2)
{
    const int bid = blockIdx.x;
    const int b = bid >> 5, cg = bid & 31;
    const int c0 = cg * 8;
    __shared__ float ss[8][841];
    __shared__ float kk[8][25];
    const int tid = threadIdx.x;
    {
        const int cl = tid >> 5, ln = tid & 31;
        const float* sp = sf + ((size_t)(b * 256 + c0 + cl)) * 841;
        for (int j = ln; j < 841; j += 32) ss[cl][j] = sp[j];
        if (tid < 200) {
            const int c = tid / 25, j = tid - c * 25;
            kk[c][j] = kf[((size_t)(b * 256 + c0 + c)) * 25 + j];
        }
    }
    __syncthreads();
    const int cc = tid & 7, tp = tid >> 3;
    for (int p = tp; p < 625; p += 32) {
        const int oh = p / 25, ow = p - oh * 25;
        const float* s = &ss[cc][oh * 29 + ow];
        float acc = 0.f;
        #pragma unroll
        for (int i = 0; i < 5; ++i)
            #pragma unroll
            for (int j = 0; j < 5; ++j)
                acc += s[i * 29 + j] * kk[cc][i * 5 + j];
        xc2[((size_t)(b * 625 + p)) * 256 + c0 + cc] = f2bf(acc);
    }
}

// ---------------------------------------------------------------------------
// head2 as MFMA: out[b,o,p] = h2w16[o,:] . y[pos,:] + h2b[o]
// y bf16 [40000][256]; h2w16 bf16 [16][256] (rows 10..15 zero).
// block = 4 waves x 64 pos; frags loaded directly from global.
// ---------------------------------------------------------------------------
__global__ __launch_bounds__(256)
void head2_mfma_kernel(const unsigned short* __restrict__ y,
                       const unsigned short* __restrict__ h2w16,
                       const float* __restrict__ h2b,
                       float* __restrict__ out, int N)
{
    const int tid = threadIdx.x, lane = tid & 63, wid = tid >> 6;
    const int pbase = blockIdx.x * 256 + wid * 64;
    const int q = lane >> 4, lr = lane & 15;

    const unsigned short* arow = h2w16 + lr * 256 + q * 8;
    const unsigned short* yrow[4];
    #pragma unroll
    for (int n = 0; n < 4; ++n) {
        int pg = pbase + n * 16 + lr; if (pg > N - 1) pg = N - 1;
        yrow[n] = y + (size_t)pg * 256 + q * 8;
    }

    f32x4 acc[4] = {};
    #pragma unroll
    for (int ks = 0; ks < 8; ++ks) {
        bf16x8 a = *(const bf16x8*)(arow + ks * 32);
        #pragma unroll
        for (int n = 0; n < 4; ++n) {
            bf16x8 bb = *(const bf16x8*)(yrow[n] + ks * 32);
            acc[n] = __builtin_amdgcn_mfma_f32_16x16x32_bf16(a, bb, acc[n], 0, 0, 0);
        }
    }

    #pragma unroll
    for (int n = 0; n < 4; ++n) {
        const int pg = pbase + n * 16 + lr;
        if (pg < N) {
            const int b = pg / 625, p = pg - b * 625;
            #pragma unroll
            for (int r = 0; r < 4; ++r) {
                const int oc = q * 4 + r;
                if (oc < 10)
                    out[((size_t)(b * 10 + oc)) * 625 + p] = acc[n][r] + h2b[oc];
            }
        }
    }
}

// ---------------------------------------------------------------------------
extern "C" void kernel_launch(void* const* d_in, const int* in_sizes, int n_in,
                              void* d_out, int out_size, void* d_ws, size_t ws_size,
                              hipStream_t stream)
{
    const float* kin  = (const float*)d_in[0];
    const float* srch = (const float*)d_in[1];
    const float* ck_w = (const float*)d_in[2];
    const float* ck_g = (const float*)d_in[3];
    const float* ck_b = (const float*)d_in[4];
    const float* ck_m = (const float*)d_in[5];
    const float* ck_v = (const float*)d_in[6];
    const float* cs_w = (const float*)d_in[7];
    const float* cs_g = (const float*)d_in[8];
    const float* cs_b = (const float*)d_in[9];
    const float* cs_m = (const float*)d_in[10];
    const float* cs_v = (const float*)d_in[11];
    const float* h1_w = (const float*)d_in[12];
    const float* h_g  = (const float*)d_in[13];
    const float* h_b  = (const float*)d_in[14];
    const float* h_m  = (const float*)d_in[15];
    const float* h_v  = (const float*)d_in[16];
    const float* h2_w = (const float*)d_in[17];
    const float* h2_b = (const float*)d_in[18];

    const int B = in_sizes[0] / (256 * 7 * 7);   // 64

    // ---- workspace layout (byte offsets), lifetime-aliased ----
    uint8_t* w = (uint8_t*)d_ws;
    unsigned short* s16   = (unsigned short*)(w);               // B*31*31*256 bf16 (31.5MB)
    unsigned short* xc2   = (unsigned short*)(w);               // 40000*256 bf16 (aliases s16)
    float*          sf    = (float*)(w + 31490048);             // B*256*841 f32 (55.1MB)
    unsigned short* y     = (unsigned short*)(w + 31490048);    // 40000*256 bf16 (aliases sf)
    float*          kf    = (float*)(w + 86605824);             // B*256*25 f32
    unsigned short* k16   = (unsigned short*)(w + 88244224);    // B*7*7*256 bf16
    unsigned short* wTk   = (unsigned short*)(w + 89849856);    // 9*256*256 bf16
    unsigned short* wTs   = (unsigned short*)(w + 91029504);    // 9*256*256 bf16
    unsigned short* h1w16 = (unsigned short*)(w + 92209152);    // 256*256 bf16
    unsigned short* h2w16 = (unsigned short*)(w + 92340224);    // 16*256 bf16

    const int Ns = B * 841;    // 53824
    const int Nk = B * 25;     // 1600
    const int Nh = B * 625;    // 40000

    dim3 blk(256, 1, 1);

    // prep
    hipLaunchKernelGGL((nhwc_kernel<31, 31>), dim3(B * 31), blk, 0, stream, srch, s16);
    hipLaunchKernelGGL((nhwc_kernel<7, 7>),   dim3(B * 7),  blk, 0, stream, kin,  k16);
    hipLaunchKernelGGL(weights_prep_kernel, dim3(4880), blk, 0, stream,
                       cs_w, ck_w, h1_w, h2_w, wTs, wTk, h1w16, h2w16);
    // kernel branch conv (bf16 MFMA) -> kf f32 [b][oc][25]
    hipLaunchKernelGGL((conv_mfma_kernel<3, 3, 7, 7, 5, 25, false>),
                       dim3(2 * ((Nk + 127) / 128)), blk, 0, stream,
                       k16, wTk, ck_g, ck_b, ck_m, ck_v, kf, (unsigned short*)nullptr, Nk);
    // search branch conv (bf16 MFMA) -> sf f32 [b][oc][841]
    hipLaunchKernelGGL((conv_mfma_kernel<3, 3, 31, 31, 29, 841, false>),
                       dim3(2 * ((Ns + 127) / 128)), blk, 0, stream,
                       s16, wTs, cs_g, cs_b, cs_m, cs_v, sf, (unsigned short*)nullptr, Ns);
    // depthwise xcorr -> xc2 bf16 [pos][256]
    hipLaunchKernelGGL(xcorr_kernel, dim3(B * 32), blk, 0, stream, sf, kf, xc2);
    // head1 1x1 conv + BN + ReLU (bf16 MFMA) -> y bf16 [pos][256]
    hipLaunchKernelGGL((conv_mfma_kernel<1, 1, 25, 25, 25, 625, true>),
                       dim3(2 * ((Nh + 127) / 128)), blk, 0, stream,
                       xc2, h1w16, h_g, h_b, h_m, h_v, (float*)nullptr, y, Nh);
    // head2 MFMA projection + bias
    hipLaunchKernelGGL(head2_mfma_kernel, dim3((Nh + 255) / 256), blk, 0, stream,
                       y, h2w16, h2_b, (float*)d_out, Nh);
}

// Round 4
// 176.433 us; speedup vs baseline: 7.5649x; 1.2367x over previous
//
#include <hip/hip_runtime.h>
#include <cstddef>
#include <cstdint>

#define BN_EPS 1e-5f

typedef __attribute__((ext_vector_type(8))) __bf16 bf16x8;
typedef __attribute__((ext_vector_type(4))) float f32x4;

__device__ inline unsigned short f2bf(float f) {
    unsigned u = __builtin_bit_cast(unsigned, f);
    unsigned r = (u + 0x7fff + ((u >> 16) & 1)) >> 16;
    return (unsigned short)r;
}

#define GLDS16(g, l)                                                        \
    __builtin_amdgcn_global_load_lds(                                       \
        (const __attribute__((address_space(1))) void*)(g),                 \
        (__attribute__((address_space(3))) void*)(l), 16, 0, 0)

// ===========================================================================
// Combined prep kernel: NHWC bf16 transforms + all weight conversions.
// Block ranges: [0,1984) nhwc31, [1984,2432) nhwc7, [2432,7312) weights.
// ===========================================================================
template<int H, int W>
__device__ inline void nhwc_body(int bh, const float* __restrict__ in,
                                 unsigned short* __restrict__ out)
{
    const int b = bh / H, h = bh - b * H;
    const int c = threadIdx.x;
    const float* src = in + ((size_t)(b * 256 + c) * H + h) * W;
    unsigned short* dst = out + (size_t)bh * W * 256 + c;
    #pragma unroll
    for (int w = 0; w < W; ++w) dst[w * 256] = f2bf(src[w]);
}

__global__ __launch_bounds__(256)
void prep_kernel(const float* __restrict__ srch, const float* __restrict__ kin,
                 const float* __restrict__ cs_w, const float* __restrict__ ck_w,
                 const float* __restrict__ h1_w, const float* __restrict__ h2_w,
                 unsigned short* __restrict__ s16, unsigned short* __restrict__ k16,
                 unsigned short* __restrict__ wTs, unsigned short* __restrict__ wTk,
                 unsigned short* __restrict__ h1w16, unsigned short* __restrict__ h2w16,
                 int G31, int G7)
{
    const int bid = blockIdx.x;
    if (bid < G31) {
        nhwc_body<31, 31>(bid, srch, s16);
    } else if (bid < G31 + G7) {
        nhwc_body<7, 7>(bid - G31, kin, k16);
    } else {
        const int i = (bid - G31 - G7) * 256 + threadIdx.x;
        if (i < 589824) {
            const int ic = i & 255, t = i >> 8, oc = t & 255, khkw = t >> 8;
            wTs[i] = f2bf(cs_w[(size_t)((oc << 8) + ic) * 9 + khkw]);
        } else if (i < 1179648) {
            const int j = i - 589824;
            const int ic = j & 255, t = j >> 8, oc = t & 255, khkw = t >> 8;
            wTk[j] = f2bf(ck_w[(size_t)((oc << 8) + ic) * 9 + khkw]);
        } else if (i < 1245184) {
            const int j = i - 1179648;
            h1w16[j] = f2bf(h1_w[j]);
        } else if (i < 1249280) {
            const int j = i - 1245184;
            const int oc = j >> 8, ic = j & 255;
            h2w16[j] = (oc < 10) ? f2bf(h2_w[oc * 256 + ic]) : (unsigned short)0;
        }
    }
}

// ===========================================================================
// Combined 3x3 MFMA conv + BN + ReLU for BOTH branches (runtime geometry).
// Blocks [0,Gs): search branch (with bijective XCD chunk swizzle + oct pairing)
// Blocks [Gs,Gs+Gk): kernel branch.
// Inner loop identical to round-3 proven kernel (bit-identical math).
// ===========================================================================
struct ConvParams {
    const unsigned short* bsrc;   // NHWC bf16 [B*IH*IW][256]
    const unsigned short* wT;     // bf16 [9][256 oc][256 ic]
    const float *bg, *bb, *bm, *bv;
    float* out;                   // f32 [b][256 oc][PPB]
    int IH, IW, OW, PPB, N;
};

__global__ __launch_bounds__(256)
void conv3x3_kernel(ConvParams S, ConvParams K, int Gs)
{
    __shared__ __align__(16) unsigned short Alds[128 * 64];
    __shared__ __align__(16) unsigned short Blds[128 * 64];

    const int tid  = threadIdx.x;
    const int lane = tid & 63;
    const int wid  = tid >> 6;

    const int raw = blockIdx.x;
    ConvParams P;
    int tileid;
    if (raw < Gs) {
        P = S;
        // bijective per-XCD chunk swizzle (m204 form) over Gs blocks
        const int q = Gs >> 3, r = Gs & 7;
        const int xcd = raw & 7, seq = raw >> 3;
        tileid = (xcd < r ? xcd * (q + 1) : r * (q + 1) + (xcd - r) * q) + seq;
    } else {
        P = K;
        tileid = raw - Gs;
    }
    // oct-paired decomposition: adjacent tiles share the same B-panel
    const int pt  = tileid >> 1;
    const int oct = tileid & 1;
    const int oc0 = oct << 7;
    const int p0  = pt << 7;

    // ---- staging maps (4 wave-issues each; 8 rows per issue) ----
    int aoff[4], brow[4], bgs8[4], ldsrow[4];
    #pragma unroll
    for (int i = 0; i < 4; ++i) {
        const int r  = i * 32 + wid * 8 + (lane >> 3);
        const int gs = (lane & 7) ^ (r & 7);
        aoff[i] = (oc0 + r) * 256 + gs * 8;
        int pg = p0 + r; if (pg > P.N - 1) pg = P.N - 1;
        const int bb_ = pg / P.PPB;
        const int p   = pg - bb_ * P.PPB;
        const int oh  = p / P.OW, ow = p - oh * P.OW;
        brow[i] = (bb_ * P.IH + oh) * P.IW + ow;
        bgs8[i] = gs * 8;
        ldsrow[i] = (i * 32 + wid * 8) * 64;
    }

    // ---- compute-phase maps ----
    const int q_  = lane >> 4;
    const int lr  = lane & 15;
    const int wm0 = (wid >> 1) * 64;
    const int wn0 = (wid & 1) * 64;
    const int g0  = q_ ^ (lane & 7);
    const int g1  = (4 + q_) ^ (lane & 7);
    const unsigned short* Abase = &Alds[(wm0 + lr) * 64];
    const unsigned short* Bbase = &Blds[(wn0 + lr) * 64];

    f32x4 acc[4][4] = {};

    int kh = 0, kw = 0;
    for (int khkw = 0; khkw < 9; ++khkw) {
        const size_t wslice = (size_t)khkw << 16;
        const int tapadd = kh * P.IW + kw;
        for (int ics = 0; ics < 4; ++ics) {
            const int ic0 = ics * 64;
            __syncthreads();
            #pragma unroll
            for (int i = 0; i < 4; ++i) {
                GLDS16(P.wT + wslice + aoff[i] + ic0, &Alds[ldsrow[i]]);
                GLDS16(P.bsrc + (size_t)(brow[i] + tapadd) * 256 + ic0 + bgs8[i],
                       &Blds[ldsrow[i]]);
            }
            __syncthreads();

            bf16x8 bfr[4][2];
            #pragma unroll
            for (int n = 0; n < 4; ++n) {
                bfr[n][0] = *(const bf16x8*)(Bbase + n * 1024 + g0 * 8);
                bfr[n][1] = *(const bf16x8*)(Bbase + n * 1024 + g1 * 8);
            }
            #pragma unroll
            for (int m = 0; m < 4; ++m) {
                bf16x8 a0 = *(const bf16x8*)(Abase + m * 1024 + g0 * 8);
                bf16x8 a1 = *(const bf16x8*)(Abase + m * 1024 + g1 * 8);
                #pragma unroll
                for (int n = 0; n < 4; ++n) {
                    acc[m][n] = __builtin_amdgcn_mfma_f32_16x16x32_bf16(
                                    a0, bfr[n][0], acc[m][n], 0, 0, 0);
                    acc[m][n] = __builtin_amdgcn_mfma_f32_16x16x32_bf16(
                                    a1, bfr[n][1], acc[m][n], 0, 0, 0);
                }
            }
        }
        if (++kw == 3) { kw = 0; ++kh; }
    }

    // ---- epilogue: BN + ReLU -> f32 [b][oc][PPB] ----
    #pragma unroll
    for (int m = 0; m < 4; ++m) {
        const int ocm = oc0 + wm0 + m * 16 + q_ * 4;
        float sc[4], sh[4];
        #pragma unroll
        for (int r = 0; r < 4; ++r) {
            sc[r] = P.bg[ocm + r] * rsqrtf(P.bv[ocm + r] + BN_EPS);
            sh[r] = P.bb[ocm + r] - P.bm[ocm + r] * sc[r];
        }
        #pragma unroll
        for (int n = 0; n < 4; ++n) {
            const int pg = p0 + wn0 + n * 16 + lr;
            if (pg < P.N) {
                const int bb_ = pg / P.PPB;
                const int p   = pg - bb_ * P.PPB;
                #pragma unroll
                for (int r = 0; r < 4; ++r)
                    P.out[((size_t)(bb_ * 256 + ocm + r)) * P.PPB + p] =
                        fmaxf(acc[m][n][r] * sc[r] + sh[r], 0.f);
            }
        }
    }
}

// ===========================================================================
// head1 1x1 conv (round-3 template, OUT_NT path)
// ===========================================================================
template<int KH, int KW, int IH, int IW, int OW, int PPB, bool OUT_NT>
__global__ __launch_bounds__(256)
void conv_mfma_kernel(const unsigned short* __restrict__ bsrc,
                      const unsigned short* __restrict__ wT,
                      const float* __restrict__ bn_g,
                      const float* __restrict__ bn_b,
                      const float* __restrict__ bn_m,
                      const float* __restrict__ bn_v,
                      float* __restrict__ out_f32,
                      unsigned short* __restrict__ out_nt,
                      int N)
{
    constexpr int KHW = KH * KW;
    __shared__ __align__(16) unsigned short Alds[128 * 64];
    __shared__ __align__(16) unsigned short Blds[128 * 64];

    const int tid  = threadIdx.x;
    const int lane = tid & 63;
    const int wid  = tid >> 6;

    const int NPT = (N + 127) >> 7;
    const int bid = blockIdx.x;
    const int pt  = bid % NPT;
    const int oct = bid / NPT;
    const int oc0 = oct * 128;
    const int p0  = pt * 128;

    int aoff[4], brow[4], bgs8[4], ldsrow[4];
    #pragma unroll
    for (int i = 0; i < 4; ++i) {
        const int r  = i * 32 + wid * 8 + (lane >> 3);
        const int gs = (lane & 7) ^ (r & 7);
        aoff[i] = (oc0 + r) * 256 + gs * 8;
        int pg = p0 + r; if (pg > N - 1) pg = N - 1;
        const int bb = pg / PPB;
        const int p  = pg - bb * PPB;
        const int oh = p / OW, ow = p - oh * OW;
        brow[i] = (bb * IH + oh) * IW + ow;
        bgs8[i] = gs * 8;
        ldsrow[i] = (i * 32 + wid * 8) * 64;
    }

    const int q   = lane >> 4;
    const int lr  = lane & 15;
    const int wm0 = (wid >> 1) * 64;
    const int wn0 = (wid & 1) * 64;
    const int g0  = q ^ (lane & 7);
    const int g1  = (4 + q) ^ (lane & 7);
    const unsigned short* Abase = &Alds[(wm0 + lr) * 64];
    const unsigned short* Bbase = &Blds[(wn0 + lr) * 64];

    f32x4 acc[4][4] = {};

    for (int khkw = 0; khkw < KHW; ++khkw) {
        const int kh = khkw / KW;
        const int kw = khkw - kh * KW;
        const size_t wslice = (size_t)khkw * 65536;
        const int tapadd = kh * IW + kw;
        for (int ics = 0; ics < 4; ++ics) {
            const int ic0 = ics * 64;
            __syncthreads();
            #pragma unroll
            for (int i = 0; i < 4; ++i) {
                GLDS16(wT + wslice + aoff[i] + ic0, &Alds[ldsrow[i]]);
                GLDS16(bsrc + (size_t)(brow[i] + tapadd) * 256 + ic0 + bgs8[i],
                       &Blds[ldsrow[i]]);
            }
            __syncthreads();

            bf16x8 bfr[4][2];
            #pragma unroll
            for (int n = 0; n < 4; ++n) {
                bfr[n][0] = *(const bf16x8*)(Bbase + n * 1024 + g0 * 8);
                bfr[n][1] = *(const bf16x8*)(Bbase + n * 1024 + g1 * 8);
            }
            #pragma unroll
            for (int m = 0; m < 4; ++m) {
                bf16x8 a0 = *(const bf16x8*)(Abase + m * 1024 + g0 * 8);
                bf16x8 a1 = *(const bf16x8*)(Abase + m * 1024 + g1 * 8);
                #pragma unroll
                for (int n = 0; n < 4; ++n) {
                    acc[m][n] = __builtin_amdgcn_mfma_f32_16x16x32_bf16(
                                    a0, bfr[n][0], acc[m][n], 0, 0, 0);
                    acc[m][n] = __builtin_amdgcn_mfma_f32_16x16x32_bf16(
                                    a1, bfr[n][1], acc[m][n], 0, 0, 0);
                }
            }
        }
    }

    #pragma unroll
    for (int m = 0; m < 4; ++m) {
        const int ocm = oc0 + wm0 + m * 16 + q * 4;
        float sc[4], sh[4];
        #pragma unroll
        for (int r = 0; r < 4; ++r) {
            sc[r] = bn_g[ocm + r] * rsqrtf(bn_v[ocm + r] + BN_EPS);
            sh[r] = bn_b[ocm + r] - bn_m[ocm + r] * sc[r];
        }
        #pragma unroll
        for (int n = 0; n < 4; ++n) {
            const int pg = p0 + wn0 + n * 16 + lr;
            if (pg < N) {
                if (OUT_NT) {
                    unsigned e0 = f2bf(fmaxf(acc[m][n][0] * sc[0] + sh[0], 0.f));
                    unsigned e1 = f2bf(fmaxf(acc[m][n][1] * sc[1] + sh[1], 0.f));
                    unsigned e2 = f2bf(fmaxf(acc[m][n][2] * sc[2] + sh[2], 0.f));
                    unsigned e3 = f2bf(fmaxf(acc[m][n][3] * sc[3] + sh[3], 0.f));
                    uint2 v; v.x = e0 | (e1 << 16); v.y = e2 | (e3 << 16);
                    *(uint2*)(out_nt + (size_t)pg * 256 + ocm) = v;
                } else {
                    const int bb = pg / PPB;
                    const int p  = pg - bb * PPB;
                    #pragma unroll
                    for (int r = 0; r < 4; ++r)
                        out_f32[((size_t)(bb * 256 + ocm + r)) * PPB + p] =
                            fmaxf(acc[m][n][r] * sc[r] + sh[r], 0.f);
                }
            }
        }
    }
}

// ===========================================================================
// Depthwise xcorr (unchanged from round 3)
// ===========================================================================
__global__ __launch_bounds__(256)
void xcorr_kernel(const float* __restrict__ sf, const float* __restrict__ kf,
                  unsigned short* __restrict__ xc2)
{
    const int bid = blockIdx.x;
    const int b = bid >> 5, cg = bid & 31;
    const int c0 = cg * 8;
    __shared__ float ss[8][841];
    __shared__ float kk[8][25];
    const int tid = threadIdx.x;
    {
        const int cl = tid >> 5, ln = tid & 31;
        const float* sp = sf + ((size_t)(b * 256 + c0 + cl)) * 841;
        for (int j = ln; j < 841; j += 32) ss[cl][j] = sp[j];
        if (tid < 200) {
            const int c = tid / 25, j = tid - c * 25;
            kk[c][j] = kf[((size_t)(b * 256 + c0 + c)) * 25 + j];
        }
    }
    __syncthreads();
    const int cc = tid & 7, tp = tid >> 3;
    for (int p = tp; p < 625; p += 32) {
        const int oh = p / 25, ow = p - oh * 25;
        const float* s = &ss[cc][oh * 29 + ow];
        float acc = 0.f;
        #pragma unroll
        for (int i = 0; i < 5; ++i)
            #pragma unroll
            for (int j = 0; j < 5; ++j)
                acc += s[i * 29 + j] * kk[cc][i * 5 + j];
        xc2[((size_t)(b * 625 + p)) * 256 + c0 + cc] = f2bf(acc);
    }
}

// ===========================================================================
// head2 MFMA projection (unchanged from round 3)
// ===========================================================================
__global__ __launch_bounds__(256)
void head2_mfma_kernel(const unsigned short* __restrict__ y,
                       const unsigned short* __restrict__ h2w16,
                       const float* __restrict__ h2b,
                       float* __restrict__ out, int N)
{
    const int tid = threadIdx.x, lane = tid & 63, wid = tid >> 6;
    const int pbase = blockIdx.x * 256 + wid * 64;
    const int q = lane >> 4, lr = lane & 15;

    const unsigned short* arow = h2w16 + lr * 256 + q * 8;
    const unsigned short* yrow[4];
    #pragma unroll
    for (int n = 0; n < 4; ++n) {
        int pg = pbase + n * 16 + lr; if (pg > N - 1) pg = N - 1;
        yrow[n] = y + (size_t)pg * 256 + q * 8;
    }

    f32x4 acc[4] = {};
    #pragma unroll
    for (int ks = 0; ks < 8; ++ks) {
        bf16x8 a = *(const bf16x8*)(arow + ks * 32);
        #pragma unroll
        for (int n = 0; n < 4; ++n) {
            bf16x8 bb = *(const bf16x8*)(yrow[n] + ks * 32);
            acc[n] = __builtin_amdgcn_mfma_f32_16x16x32_bf16(a, bb, acc[n], 0, 0, 0);
        }
    }

    #pragma unroll
    for (int n = 0; n < 4; ++n) {
        const int pg = pbase + n * 16 + lr;
        if (pg < N) {
            const int b = pg / 625, p = pg - b * 625;
            #pragma unroll
            for (int r = 0; r < 4; ++r) {
                const int oc = q * 4 + r;
                if (oc < 10)
                    out[((size_t)(b * 10 + oc)) * 625 + p] = acc[n][r] + h2b[oc];
            }
        }
    }
}

// ===========================================================================
extern "C" void kernel_launch(void* const* d_in, const int* in_sizes, int n_in,
                              void* d_out, int out_size, void* d_ws, size_t ws_size,
                              hipStream_t stream)
{
    const float* kin  = (const float*)d_in[0];
    const float* srch = (const float*)d_in[1];
    const float* ck_w = (const float*)d_in[2];
    const float* ck_g = (const float*)d_in[3];
    const float* ck_b = (const float*)d_in[4];
    const float* ck_m = (const float*)d_in[5];
    const float* ck_v = (const float*)d_in[6];
    const float* cs_w = (const float*)d_in[7];
    const float* cs_g = (const float*)d_in[8];
    const float* cs_b = (const float*)d_in[9];
    const float* cs_m = (const float*)d_in[10];
    const float* cs_v = (const float*)d_in[11];
    const float* h1_w = (const float*)d_in[12];
    const float* h_g  = (const float*)d_in[13];
    const float* h_b  = (const float*)d_in[14];
    const float* h_m  = (const float*)d_in[15];
    const float* h_v  = (const float*)d_in[16];
    const float* h2_w = (const float*)d_in[17];
    const float* h2_b = (const float*)d_in[18];

    const int B = in_sizes[0] / (256 * 7 * 7);   // 64

    // ---- workspace layout (identical to round 3) ----
    uint8_t* w = (uint8_t*)d_ws;
    unsigned short* s16   = (unsigned short*)(w);               // B*31*31*256 bf16
    unsigned short* xc2   = (unsigned short*)(w);               // aliases s16
    float*          sf    = (float*)(w + 31490048);             // B*256*841 f32
    unsigned short* y     = (unsigned short*)(w + 31490048);    // aliases sf
    float*          kf    = (float*)(w + 86605824);             // B*256*25 f32
    unsigned short* k16   = (unsigned short*)(w + 88244224);    // B*7*7*256 bf16
    unsigned short* wTk   = (unsigned short*)(w + 89849856);
    unsigned short* wTs   = (unsigned short*)(w + 91029504);
    unsigned short* h1w16 = (unsigned short*)(w + 92209152);
    unsigned short* h2w16 = (unsigned short*)(w + 92340224);

    const int Ns = B * 841;    // 53824
    const int Nk = B * 25;     // 1600
    const int Nh = B * 625;    // 40000
    const int Gs = 2 * ((Ns + 127) / 128);   // 842
    const int Gk = 2 * ((Nk + 127) / 128);   // 26
    const int G31 = B * 31, G7 = B * 7;

    dim3 blk(256, 1, 1);

    // 1) prep: NHWC transforms + weight conversions (one launch)
    hipLaunchKernelGGL(prep_kernel, dim3(G31 + G7 + 4880), blk, 0, stream,
                       srch, kin, cs_w, ck_w, h1_w, h2_w,
                       s16, k16, wTs, wTk, h1w16, h2w16, G31, G7);

    // 2) both 3x3 convs in one launch
    ConvParams S{ s16, wTs, cs_g, cs_b, cs_m, cs_v, sf, 31, 31, 29, 841, Ns };
    ConvParams K{ k16, wTk, ck_g, ck_b, ck_m, ck_v, kf, 7, 7, 5, 25, Nk };
    hipLaunchKernelGGL(conv3x3_kernel, dim3(Gs + Gk), blk, 0, stream, S, K, Gs);

    // 3) depthwise xcorr -> xc2 bf16 [pos][256]
    hipLaunchKernelGGL(xcorr_kernel, dim3(B * 32), blk, 0, stream, sf, kf, xc2);

    // 4) head1 1x1 conv + BN + ReLU -> y bf16 [pos][256]
    hipLaunchKernelGGL((conv_mfma_kernel<1, 1, 25, 25, 25, 625, true>),
                       dim3(2 * ((Nh + 127) / 128)), blk, 0, stream,
                       xc2, h1w16, h_g, h_b, h_m, h_v, (float*)nullptr, y, Nh);

    // 5) head2 projection + bias
    hipLaunchKernelGGL(head2_mfma_kernel, dim3((Nh + 255) / 256), blk, 0, stream,
                       y, h2w16, h2_b, (float*)d_out, Nh);
}